// Round 5
// baseline (108.808 us; speedup 1.0000x reference)
//
#include <hip/hip_runtime.h>

#define HH 256
#define WW 512
#define CC 64
#define CO 16
#define DD 48            // MAX_DISPARITY; output has ND = 49 disparity planes
#define ND (DD + 1)
#define YQ 8             // y-chunks per plane
#define ROWS (HH / YQ)   // 32 rows per block

typedef float f32x4 __attribute__((ext_vector_type(4)));

// Kernel 1: per-pixel 16x64 matvec for both L and R projections.
__global__ __launch_bounds__(256) void lr_project(
    const float* __restrict__ left, const float* __restrict__ right,
    const float* __restrict__ Wop,
    float* __restrict__ Lout, float* __restrict__ Rout)
{
    const int tid = blockIdx.x * blockDim.x + threadIdx.x;  // 0 .. H*W-1
    const int x = tid & (WW - 1);
    const int y = tid >> 9;   // /512

    float accL[CO], accR[CO];
#pragma unroll
    for (int o = 0; o < CO; ++o) { accL[o] = 0.0f; accR[o] = 0.0f; }

#pragma unroll 4
    for (int c = 0; c < CC; ++c) {
        const float l = left [(c * HH + y) * WW + x];
        const float r = right[(c * HH + y) * WW + x];
#pragma unroll
        for (int o = 0; o < CO; ++o) {
            accL[o] += Wop[o * (2 * CC) + c]      * l;
            accR[o] += Wop[o * (2 * CC) + CC + c] * r;
        }
    }

#pragma unroll
    for (int o = 0; o < CO; ++o) {
        Lout[(o * HH + y) * WW + x] = accL[o];
        Rout[(o * HH + y) * WW + x] = accR[o];
    }
}

// Kernel 2: out[o,d,y,x] = L[o,y,x] + (x>=d ? R[o,y,x-d] : 0) + b[o]
// Block = (o, d, y-eighth): writes a CONTIGUOUS 64 KB output slab,
// advancing monotonically (fill-kernel-like write locality).
// d is block-uniform -> R read is a contiguous row at offset -d (L2-hit).
// o is mapped to blockIdx%8 so each XCD's L2 holds only 2 (L,R) plane pairs.
__global__ __launch_bounds__(256) void assemble(
    const float* __restrict__ L, const float* __restrict__ R,
    const float* __restrict__ bop, float* __restrict__ out)
{
    // blockIdx.x = g + 8*(oh*392 + d*8 + yq), g = XCD slot
    const int g  = blockIdx.x & 7;
    const int j  = blockIdx.x >> 3;          // 0..783
    const int oh = j / 392;                  // 0..1
    const int r  = j - 392 * oh;
    const int d  = r >> 3;                   // 0..48
    const int yq = r & 7;                    // 0..7
    const int o  = g + 8 * oh;               // 0..15

    const int t   = threadIdx.x;
    const int x   = (t & 127) << 2;          // 0..508, step 4
    const int yr0 = t >> 7;                  // 0 or 1
    const int y0  = yq * ROWS + yr0;

    const float b = bop[o];

    // per-thread constant boundary masks (x, d fixed)
    const float m0 = (x + 0 >= d) ? 1.0f : 0.0f;
    const float m1 = (x + 1 >= d) ? 1.0f : 0.0f;
    const float m2 = (x + 2 >= d) ? 1.0f : 0.0f;
    const float m3 = (x + 3 >= d) ? 1.0f : 0.0f;

    const float* Lp = &L[(o * HH + y0) * WW + x];
    const float* Rp = Lp + ((const float*)R - (const float*)L) - d;  // R row, shifted
    float*       op = &out[((size_t)(o * ND + d) * HH + y0) * WW + x];

#pragma unroll
    for (int k = 0; k < ROWS / 2; ++k) {     // 16 iters, 2-row stride
        const f32x4 lv = *reinterpret_cast<const f32x4*>(Lp);
        f32x4 rv;                             // 4B-aligned load (x-d offset)
        __builtin_memcpy(&rv, Rp, sizeof(rv));

        f32x4 ov;
        ov.x = lv.x + b + m0 * rv.x;
        ov.y = lv.y + b + m1 * rv.y;
        ov.z = lv.z + b + m2 * rv.z;
        ov.w = lv.w + b + m3 * rv.w;
        __builtin_nontemporal_store(ov, reinterpret_cast<f32x4*>(op));

        Lp += 2 * WW;
        Rp += 2 * WW;
        op += 2 * WW;
    }
}

extern "C" void kernel_launch(void* const* d_in, const int* in_sizes, int n_in,
                              void* d_out, int out_size, void* d_ws, size_t ws_size,
                              hipStream_t stream) {
    const float* left  = (const float*)d_in[0];
    const float* right = (const float*)d_in[1];
    const float* Wop   = (const float*)d_in[2];
    const float* bop   = (const float*)d_in[3];
    float* out = (float*)d_out;

    float* Lws = (float*)d_ws;                      // CO*H*W floats = 8 MB
    float* Rws = Lws + (size_t)CO * HH * WW;        // next 8 MB
    // NOTE: speculative R reads reach back at most 48 floats before Rws,
    // which lands inside Lws — valid memory.

    lr_project<<<(HH * WW) / 256, 256, 0, stream>>>(left, right, Wop, Lws, Rws);

    // 16 o * 49 d * 8 yq = 6272 blocks
    assemble<<<CO * ND * YQ, 256, 0, stream>>>(Lws, Rws, bop, out);
}